// Round 16
// baseline (341.227 us; speedup 1.0000x reference)
//
#include <hip/hip_runtime.h>
#include <math.h>

static constexpr int NN = 50000;     // nodes
static constexpr long NE = 800000;   // edges
static constexpr int FF = 64;        // features
static constexpr int EDIM = 16;      // edge attr dim
static constexpr int NLAYER = 2;
static constexpr float EPSBN = 1e-5f;
static constexpr int NGRP = NN / 16;         // 3125 node groups of 16
static constexpr int SCB = 512;              // scan block size
static constexpr int NSCB = (NN + SCB - 1) / SCB;  // 98
static constexpr int LDSW = 68;              // LDS row stride (floats): 2-way bank aliasing only
static constexpr int WFRAG = 28672;          // shorts per Wc fragment set (14kc x 4nt x 64 x 8)
static constexpr size_t NODE_LDS = (size_t)WFRAG * 2 * 2 + 512;  // BH+BL + sS/sQ = 115200 B

typedef __attribute__((ext_vector_type(8))) short short8v;
typedef __attribute__((ext_vector_type(4))) float f32x4;

#define MFMA16(a, b, c) __builtin_amdgcn_mfma_f32_16x16x32_bf16(a, b, c, 0, 0, 0)

__device__ __forceinline__ short f2bf(float f) {
    unsigned u = __float_as_uint(f);
    unsigned r = u + 0x7FFFu + ((u >> 16) & 1u);   // RNE
    return (short)(r >> 16);
}
__device__ __forceinline__ float bf2f(unsigned short h) {
    return __uint_as_float(((unsigned)h) << 16);
}
__device__ __forceinline__ unsigned pk2(float lo, float hi) {
    return (unsigned)(unsigned short)f2bf(lo) | ((unsigned)(unsigned short)f2bf(hi) << 16);
}
__device__ __forceinline__ short8v pack8(const float* p) {
    const float4* q = (const float4*)p;
    float4 a = q[0], b = q[1];
    short8v v;
    v[0] = f2bf(a.x); v[1] = f2bf(a.y); v[2] = f2bf(a.z); v[3] = f2bf(a.w);
    v[4] = f2bf(b.x); v[5] = f2bf(b.y); v[6] = f2bf(b.z); v[7] = f2bf(b.w);
    return v;
}
// BN+ReLU applied during pack: y = max(v*s + o, 0); s=sc[f0+j], o=sc[64+f0+j]
__device__ __forceinline__ short8v pack8bn(const float* p, const float* sc, int f0) {
    const float4* q = (const float4*)p;
    float4 a = q[0], b = q[1];
    float v[8] = {a.x, a.y, a.z, a.w, b.x, b.y, b.z, b.w};
    short8v r;
#pragma unroll
    for (int j = 0; j < 8; ++j) {
        float y = fmaxf(fmaf(v[j], sc[f0 + j], sc[FF + f0 + j]), 0.f);
        r[j] = f2bf(y);
    }
    return r;
}
// split pack: hi = bf16(v), lo = bf16(v - hi)
__device__ __forceinline__ void pack8s(const float* p, short8v& hi, short8v& lo) {
    const float4* q = (const float4*)p;
    float4 a = q[0], b = q[1];
    float v[8] = {a.x, a.y, a.z, a.w, b.x, b.y, b.z, b.w};
#pragma unroll
    for (int j = 0; j < 8; ++j) {
        short h = f2bf(v[j]);
        hi[j] = h;
        lo[j] = f2bf(v[j] - bf2f((unsigned short)h));
    }
}
__device__ __forceinline__ void pack8s_bn(const float* p, const float* sc, int f0,
                                          short8v& hi, short8v& lo) {
    const float4* q = (const float4*)p;
    float4 a = q[0], b = q[1];
    float v[8] = {a.x, a.y, a.z, a.w, b.x, b.y, b.z, b.w};
#pragma unroll
    for (int j = 0; j < 8; ++j) {
        float y = fmaxf(fmaf(v[j], sc[f0 + j], sc[FF + f0 + j]), 0.f);
        short h = f2bf(y);
        hi[j] = h;
        lo[j] = f2bf(y - bf2f((unsigned short)h));
    }
}
__device__ __forceinline__ void pack8fs(const float* v, short8v& hi, short8v& lo) {
#pragma unroll
    for (int j = 0; j < 8; ++j) {
        short h = f2bf(v[j]);
        hi[j] = h;
        lo[j] = f2bf(v[j] - bf2f((unsigned short)h));
    }
}

// ---- fold weights (32 blocks: 2 layers x 16 slices) ----
__global__ void fold_kernel(const float* __restrict__ We, const float* __restrict__ be,
                            const float* __restrict__ Wpre, const float* __restrict__ bpre,
                            const float* __restrict__ Wpost, const float* __restrict__ bpost,
                            const float* __restrict__ Wlin, const float* __restrict__ blin,
                            float* __restrict__ Weff, float* __restrict__ beff,
                            float* __restrict__ Wc, float* __restrict__ cfold) {
    int l = blockIdx.x >> 4;
    int s = blockIdx.x & 15;
    int t = threadIdx.x;
    const float* We_l    = We    + l * EDIM * FF;
    const float* Wpre_e  = Wpre  + l * 2 * FF * FF + FF * FF;  // rows 64..127
    const float* Wpost_l = Wpost + l * 7 * FF * FF;
    const float* Wlin_l  = Wlin  + l * FF * FF;

    __shared__ float slin[FF * FF];
    __shared__ float spre[FF * FF];
    for (int i = t; i < FF * FF; i += blockDim.x) { slin[i] = Wlin_l[i]; spre[i] = Wpre_e[i]; }
    __syncthreads();

    for (int i = s * 256 + t; i < EDIM * FF; i += 16 * 256) {
        int j = i >> 6, f = i & 63;
        float a = 0.f;
        for (int k = 0; k < FF; ++k) a += We_l[j * FF + k] * spre[k * FF + f];
        Weff[l * EDIM * FF + i] = a;
    }
    for (int i = s * 256 + t; i < FF; i += 16 * 256) {
        float a = bpre[l * FF + i];
        for (int k = 0; k < FF; ++k) a += be[l * FF + k] * spre[k * FF + i];
        beff[l * FF + i] = a;
    }
    for (int i = s * 256 + t; i < 7 * FF * FF; i += 16 * 256) {
        int r = i >> 6, f = i & 63;
        float a = 0.f;
        for (int k = 0; k < FF; ++k) a += Wpost_l[r * FF + k] * slin[k * FF + f];
        Wc[l * 7 * FF * FF + i] = a;
    }
    for (int i = s * 256 + t; i < FF; i += 16 * 256) {
        float a = blin[l * FF + i];
        for (int k = 0; k < FF; ++k) a += bpost[l * FF + k] * slin[k * FF + i];
        cfold[l * FF + i] = a;
    }
}

// ---- all weight fragments in one launch. 34 blocks: 2 layers x (2 Wpre + 1 Weff + 14 Wc)
__global__ void fragify_all(const float* __restrict__ Wpre, const float* __restrict__ Weff,
                            const float* __restrict__ Wc,
                            short* __restrict__ WpreF, short* __restrict__ WeffF,
                            short* __restrict__ WcFh, short* __restrict__ WcFl) {
    int b = blockIdx.x;          // 0..33
    int l = b / 17, r = b % 17;
    int t = threadIdx.x;
    const float* src; short* dh; short* dl = nullptr; int kc, Kreal;
    if (r < 2)      { src = Wpre + (size_t)l * 2 * FF * FF; dh = WpreF + l * 4096;  kc = r;     Kreal = 64; }
    else if (r < 3) { src = Weff + (size_t)l * EDIM * FF;   dh = WeffF + l * 2048;  kc = 0;     Kreal = 16; }
    else            { src = Wc   + (size_t)l * 7 * FF * FF; dh = WcFh + l * WFRAG;
                      dl = WcFl + l * WFRAG;                                        kc = r - 3; Kreal = 448; }
    int idx = kc * 256 + t;
    int lane = idx & 63, nt = (idx >> 6) & 3;
    int m = lane & 15, kh = lane >> 4;
    short8v hv, lv;
#pragma unroll
    for (int j = 0; j < 8; ++j) {
        int k = kc * 32 + kh * 8 + j;
        float val = (k < Kreal) ? src[k * FF + nt * 16 + m] : 0.f;
        short h = f2bf(val);
        hv[j] = h;
        lv[j] = f2bf(val - bf2f((unsigned short)h));
    }
    ((short8v*)dh)[idx] = hv;
    if (dl) ((short8v*)dl)[idx] = lv;
}

// ================= CSR build phase ==========

__global__ void build_zero(int* __restrict__ rowcnt, int* __restrict__ fill,
                           int* __restrict__ bc, float* __restrict__ avglog) {
    long i = (long)blockIdx.x * 256 + threadIdx.x;
    long stride = (long)gridDim.x * 256;
    for (long j = i; j < NN; j += stride) { rowcnt[j] = 0; fill[j] = 0; bc[j] = 0; }
    if (i == 0) avglog[0] = 0.f;
}

__global__ void hist_dst(const int* __restrict__ ei, int* __restrict__ rowcnt) {
    long e = (long)blockIdx.x * 256 + threadIdx.x;
    if (e < NE) atomicAdd(&rowcnt[ei[NE + e]], 1);
}

// ---- hierarchical exclusive scan: rowcnt[NN] -> rowptr[NN+1] ----
__global__ void scan_a(const int* __restrict__ rowcnt, int* __restrict__ part) {
    __shared__ int red[SCB];
    int t = threadIdx.x;
    int i = blockIdx.x * SCB + t;
    red[t] = (i < NN) ? rowcnt[i] : 0;
    __syncthreads();
    for (int o = SCB / 2; o > 0; o >>= 1) {
        if (t < o) red[t] += red[t + o];
        __syncthreads();
    }
    if (t == 0) part[blockIdx.x] = red[0];
}

__global__ void scan_b(int* __restrict__ part, int* __restrict__ rowptr) {
    __shared__ int s[128];
    int t = threadIdx.x;
    int v = (t < NSCB) ? part[t] : 0;
    s[t] = v;
    __syncthreads();
    for (int o = 1; o < 128; o <<= 1) {
        int u = (t >= o) ? s[t - o] : 0;
        __syncthreads();
        s[t] += u;
        __syncthreads();
    }
    if (t < NSCB) part[t] = s[t] - v;          // exclusive block offset
    if (t == 127) rowptr[NN] = s[127];         // total
}

__global__ void scan_c(const int* __restrict__ rowcnt, const int* __restrict__ part,
                       int* __restrict__ rowptr) {
    __shared__ int s[SCB];
    int t = threadIdx.x;
    int i = blockIdx.x * SCB + t;
    int v = (i < NN) ? rowcnt[i] : 0;
    s[t] = v;
    __syncthreads();
    for (int o = 1; o < SCB; o <<= 1) {
        int u = (t >= o) ? s[t - o] : 0;
        __syncthreads();
        s[t] += u;
        __syncthreads();
    }
    if (i < NN) rowptr[i] = part[blockIdx.x] + s[t] - v;
}

// phase 1: scatter only an 8B (src, edge-id) record to the CSR slot
__global__ void scatter_perm(const int* __restrict__ ei, const int* __restrict__ rowptr,
                             int* __restrict__ fill, int2* __restrict__ srcperm) {
    long e = (long)blockIdx.x * 256 + threadIdx.x;
    if (e >= NE) return;
    int d = ei[NE + e];
    int p = rowptr[d] + atomicAdd(&fill[d], 1);
    srcperm[p] = make_int2(ei[e], (int)e);
}

// phase 2: sequential CSR positions -> coalesced srcp/attrb writes; random attr READS
__global__ void gather_attr(const int2* __restrict__ srcperm, const float* __restrict__ attr,
                            int* __restrict__ srcp, short* __restrict__ attrb) {
    long p = (long)blockIdx.x * 256 + threadIdx.x;
    if (p >= NE) return;
    int2 sp = srcperm[p];
    srcp[p] = sp.x;
    long e = sp.y;
    const float4* a4 = (const float4*)(attr + e * EDIM);
    float4 A = a4[0], B = a4[1], C = a4[2], D = a4[3];
    uint4 w0, w1;
    w0.x = pk2(A.x, A.y); w0.y = pk2(A.z, A.w); w0.z = pk2(B.x, B.y); w0.w = pk2(B.z, B.w);
    w1.x = pk2(C.x, C.y); w1.y = pk2(C.z, C.w); w1.z = pk2(D.x, D.y); w1.w = pk2(D.z, D.w);
    uint4* dst = (uint4*)(attrb + p * EDIM);
    dst[0] = w0; dst[1] = w1;
}

// LDS-privatized degree histogram
__global__ void degbc2(const int* __restrict__ rowcnt, int* __restrict__ bc) {
    __shared__ int h[256];
    int t = threadIdx.x;
    h[t] = 0;
    __syncthreads();
    for (long n = (long)blockIdx.x * 256 + t; n < NN; n += (long)gridDim.x * 256) {
        int d = rowcnt[n];
        if (d < 256) {
            atomicAdd(&h[d], 1);
        } else {
            if (d >= NN) d = NN - 1;
            atomicAdd(&bc[d], 1);
        }
    }
    __syncthreads();
    int v = h[t];
    if (v) atomicAdd(&bc[t], v);
}

__global__ void avglog_kernel(const int* __restrict__ bc, float* __restrict__ total) {
    float s = 0.f;
    for (long i = (long)blockIdx.x * 256 + threadIdx.x; i < NN; i += (long)gridDim.x * 256)
        s += logf((float)bc[i] + 1.f);
    for (int o = 32; o; o >>= 1) s += __shfl_down(s, o, 64);
    __shared__ float wsum[4];
    int lane = threadIdx.x & 63, wid = threadIdx.x >> 6;
    if (lane == 0) wsum[wid] = s;
    __syncthreads();
    if (threadIdx.x == 0) atomicAdd(total, wsum[0] + wsum[1] + wsum[2] + wsum[3]);
}

__global__ void amp_kernel(const int* __restrict__ cnt, const float* __restrict__ total,
                           float* __restrict__ amp) {
    long n = (long)blockIdx.x * 256 + threadIdx.x;
    if (n < NN) {
        float avg = total[0] / (float)NN;
        float sc = fmaxf((float)cnt[n], 1.f);
        amp[n] = logf(sc + 1.f) / avg;
    }
}

// ================= per-layer kernels ==========

// xp = BN?(xin) @ Wpre[0:64] -> bf16, via MFMA. wave per 16-node group.
// block 0 zeroes the 8-way replicated BN partial array (1024 floats).
__global__ __launch_bounds__(256) void xp_mfma(const float* __restrict__ xin,
                                               const float* __restrict__ bnsc,
                                               const short* __restrict__ WF,
                                               short* __restrict__ xpb,
                                               float* __restrict__ bnsumR) {
    int t = threadIdx.x;
    if (blockIdx.x == 0) {
        for (int i = t; i < 1024; i += 256) bnsumR[i] = 0.f;
    }
    int g = blockIdx.x * 4 + (t >> 6);
    if (g >= NGRP) return;
    int lane = t & 63, m = lane & 15, kh = lane >> 4;
    const float* xr = xin + (long)(g * 16 + m) * FF;
    short8v a0, a1;
    if (bnsc) {
        a0 = pack8bn(xr + kh * 8, bnsc, kh * 8);
        a1 = pack8bn(xr + 32 + kh * 8, bnsc, 32 + kh * 8);
    } else {
        a0 = pack8(xr + kh * 8);
        a1 = pack8(xr + 32 + kh * 8);
    }
    const short8v* BF = (const short8v*)WF;
    f32x4 acc[4];
#pragma unroll
    for (int nt = 0; nt < 4; ++nt) {
        f32x4 z = {0.f, 0.f, 0.f, 0.f};
        z = MFMA16(a0, BF[(0 * 4 + nt) * 64 + lane], z);
        z = MFMA16(a1, BF[(1 * 4 + nt) * 64 + lane], z);
        acc[nt] = z;
    }
#pragma unroll
    for (int nt = 0; nt < 4; ++nt)
#pragma unroll
        for (int r = 0; r < 4; ++r) {
            long node = g * 16 + kh * 4 + r;
            xpb[node * FF + nt * 16 + m] = f2bf(acc[nt][r]);
        }
}

// FUSED edge pipeline (R13 one-node-per-wave form): per 16-edge CSR batch,
// ep = attrb@Weff + beff via MFMA staged in padded LDS, then lane=feature serial
// reduce with 8 independent gathers in flight.
__global__ __launch_bounds__(256) void agg_fused(
    const int* __restrict__ rowptr, const int* __restrict__ srcp,
    const short* __restrict__ attrb, const short* __restrict__ WF,
    const float* __restrict__ beff_l, const short* __restrict__ xpb,
    float* __restrict__ meanb, float* __restrict__ mnb, float* __restrict__ mxb) {
    __shared__ float eph[4][16 * LDSW];
    int t = threadIdx.x;
    int wid = t >> 6, lane = t & 63;
    int m = lane & 15, kh = lane >> 4;
    int n = blockIdx.x * 4 + wid;
    if (n >= NN) return;   // no barriers in this kernel; waves independent
    float* lds = &eph[wid][0];
    const short8v* BF = (const short8v*)WF;
    float bfv[4];
#pragma unroll
    for (int nt = 0; nt < 4; ++nt) bfv[nt] = beff_l[nt * 16 + m];
    long r0 = rowptr[n], r1 = rowptr[n + 1];
    const float INF = __builtin_huge_valf();
    float sm = 0.f, mn = INF, mx = -INF;
    const unsigned short* xu = (const unsigned short*)xpb + lane;  // per-lane base

    for (long base = r0; base < r1; base += 16) {
        int cnt = (int)(((r1 - base) < 16) ? (r1 - base) : 16);
        long ea = base + m; if (ea > NE - 1) ea = NE - 1;   // tail rows masked later
        short8v a;
        if (kh < 2) {
            a = *(const short8v*)(attrb + ea * EDIM + kh * 8);
        } else {
#pragma unroll
            for (int j = 0; j < 8; ++j) a[j] = 0;
        }
        f32x4 ac0, ac1, ac2, ac3;
        {
            f32x4 z = {0.f, 0.f, 0.f, 0.f};
            ac0 = MFMA16(a, BF[0 * 64 + lane], z);
            ac1 = MFMA16(a, BF[1 * 64 + lane], z);
            ac2 = MFMA16(a, BF[2 * 64 + lane], z);
            ac3 = MFMA16(a, BF[3 * 64 + lane], z);
        }
#pragma unroll
        for (int r = 0; r < 4; ++r) {
            lds[(kh * 4 + r) * LDSW + 0 * 16 + m] = ac0[r] + bfv[0];
            lds[(kh * 4 + r) * LDSW + 1 * 16 + m] = ac1[r] + bfv[1];
            lds[(kh * 4 + r) * LDSW + 2 * 16 + m] = ac2[r] + bfv[2];
            lds[(kh * 4 + r) * LDSW + 3 * 16 + m] = ac3[r] + bfv[3];
        }
        int sv = srcp[base + (lane < cnt ? lane : cnt - 1)];
        int j = 0;
        for (; j + 8 <= cnt; j += 8) {
            unsigned o0 = (unsigned)__shfl(sv, j + 0) << 6;
            unsigned o1 = (unsigned)__shfl(sv, j + 1) << 6;
            unsigned o2 = (unsigned)__shfl(sv, j + 2) << 6;
            unsigned o3 = (unsigned)__shfl(sv, j + 3) << 6;
            unsigned o4 = (unsigned)__shfl(sv, j + 4) << 6;
            unsigned o5 = (unsigned)__shfl(sv, j + 5) << 6;
            unsigned o6 = (unsigned)__shfl(sv, j + 6) << 6;
            unsigned o7 = (unsigned)__shfl(sv, j + 7) << 6;
            float x0 = bf2f(xu[o0]);
            float x1 = bf2f(xu[o1]);
            float x2 = bf2f(xu[o2]);
            float x3 = bf2f(xu[o3]);
            float x4 = bf2f(xu[o4]);
            float x5 = bf2f(xu[o5]);
            float x6 = bf2f(xu[o6]);
            float x7 = bf2f(xu[o7]);
            float h0 = x0 + lds[(j + 0) * LDSW + lane];
            float h1 = x1 + lds[(j + 1) * LDSW + lane];
            float h2 = x2 + lds[(j + 2) * LDSW + lane];
            float h3 = x3 + lds[(j + 3) * LDSW + lane];
            float h4 = x4 + lds[(j + 4) * LDSW + lane];
            float h5 = x5 + lds[(j + 5) * LDSW + lane];
            float h6 = x6 + lds[(j + 6) * LDSW + lane];
            float h7 = x7 + lds[(j + 7) * LDSW + lane];
            sm += ((h0 + h1) + (h2 + h3)) + ((h4 + h5) + (h6 + h7));
            mn = fminf(mn, fminf(fminf(fminf(h0, h1), fminf(h2, h3)),
                                 fminf(fminf(h4, h5), fminf(h6, h7))));
            mx = fmaxf(mx, fmaxf(fmaxf(fmaxf(h0, h1), fmaxf(h2, h3)),
                                 fmaxf(fmaxf(h4, h5), fmaxf(h6, h7))));
        }
        for (; j < cnt; ++j) {
            unsigned o0 = (unsigned)__shfl(sv, j) << 6;
            float h = bf2f(xu[o0]) + lds[j * LDSW + lane];
            sm += h;
            mn = fminf(mn, h);
            mx = fmaxf(mx, h);
        }
    }
    int deg = (int)(r1 - r0);
    float inv = (deg > 0) ? (1.f / (float)deg) : 0.f;
    if (deg == 0) { mn = 0.f; mx = 0.f; }
    long o = (long)n * FF + lane;
    meanb[o] = sm * inv; mnb[o] = mn; mxb[o] = mx;
}

// node GEMM v6: 256 threads (proven VGPR regime), FULL Wc fragment set (114.7KB) in
// dynamic LDS shared by 4 waves. grid 256 = 1 block/CU; each wave grid-strides over
// ~3 groups with the exact v4 dataflow (dual chains, packs). Kills the per-wave 168KB
// L2 weight stream (525MB -> 29MB). BN partials: reg accum -> LDS -> 8-replica atomics.
__global__ __launch_bounds__(256) void node_mfma6(
    const float* __restrict__ xin, const float* __restrict__ bnsc,
    const float* __restrict__ meanb, const float* __restrict__ mnb,
    const float* __restrict__ mxb, const float* __restrict__ amp,
    const short* __restrict__ WFh, const short* __restrict__ WFl,
    const float* __restrict__ cfold_l,
    float* __restrict__ out_pre, float* __restrict__ bnsumR) {
    extern __shared__ short wlds[];                 // [BH WFRAG | BL WFRAG] + sS/sQ
    float* sS = (float*)(wlds + 2 * WFRAG);         // [64]
    float* sQ = sS + 64;                            // [64]
    int t = threadIdx.x;
    int w = t >> 6, lane = t & 63, m = lane & 15, kh = lane >> 4;
    {
        const short8v* gh = (const short8v*)WFh;
        const short8v* gl = (const short8v*)WFl;
        short8v* dh = (short8v*)wlds;
        short8v* dl = (short8v*)(wlds + WFRAG);
        for (int i = t; i < WFRAG / 8; i += 256) {  // 3584 = 14 iters x 256
            dh[i] = gh[i];
            dl[i] = gl[i];
        }
    }
    if (t < 64) { sS[t] = 0.f; sQ[t] = 0.f; }
    __syncthreads();
    const short8v* BH = (const short8v*)wlds;
    const short8v* BL = (const short8v*)(wlds + WFRAG);
    float cfv[4];
#pragma unroll
    for (int nt = 0; nt < 4; ++nt) cfv[nt] = cfold_l[nt * 16 + m];
    float bs[4] = {0.f, 0.f, 0.f, 0.f}, bq[4] = {0.f, 0.f, 0.f, 0.f};

    for (int g = blockIdx.x * 4 + w; g < NGRP; g += 1024) {
        long n = (long)g * 16 + m;
        float av = amp[n];
        const float* xr = xin + n * FF;
        float vme[16], vmn[16], vmx[16], sc16[16];
        {
            const float4* s4a = (const float4*)(meanb + n * FF + kh * 8);
            const float4* s4b = (const float4*)(meanb + n * FF + 32 + kh * 8);
            float4 a = s4a[0], b = s4a[1], c = s4b[0], d = s4b[1];
            vme[0]=a.x; vme[1]=a.y; vme[2]=a.z; vme[3]=a.w;
            vme[4]=b.x; vme[5]=b.y; vme[6]=b.z; vme[7]=b.w;
            vme[8]=c.x; vme[9]=c.y; vme[10]=c.z; vme[11]=c.w;
            vme[12]=d.x; vme[13]=d.y; vme[14]=d.z; vme[15]=d.w;
        }
        {
            const float4* s4a = (const float4*)(mnb + n * FF + kh * 8);
            const float4* s4b = (const float4*)(mnb + n * FF + 32 + kh * 8);
            float4 a = s4a[0], b = s4a[1], c = s4b[0], d = s4b[1];
            vmn[0]=a.x; vmn[1]=a.y; vmn[2]=a.z; vmn[3]=a.w;
            vmn[4]=b.x; vmn[5]=b.y; vmn[6]=b.z; vmn[7]=b.w;
            vmn[8]=c.x; vmn[9]=c.y; vmn[10]=c.z; vmn[11]=c.w;
            vmn[12]=d.x; vmn[13]=d.y; vmn[14]=d.z; vmn[15]=d.w;
        }
        {
            const float4* s4a = (const float4*)(mxb + n * FF + kh * 8);
            const float4* s4b = (const float4*)(mxb + n * FF + 32 + kh * 8);
            float4 a = s4a[0], b = s4a[1], c = s4b[0], d = s4b[1];
            vmx[0]=a.x; vmx[1]=a.y; vmx[2]=a.z; vmx[3]=a.w;
            vmx[4]=b.x; vmx[5]=b.y; vmx[6]=b.z; vmx[7]=b.w;
            vmx[8]=c.x; vmx[9]=c.y; vmx[10]=c.z; vmx[11]=c.w;
            vmx[12]=d.x; vmx[13]=d.y; vmx[14]=d.z; vmx[15]=d.w;
        }
        f32x4 accA[4], accB[4];
#pragma unroll
        for (int nt = 0; nt < 4; ++nt) {
            f32x4 z = {0.f, 0.f, 0.f, 0.f};
            accA[nt] = z; accB[nt] = z;
        }
        short8v hv, lv;
#define DO_KC3(kc, ACC) { \
        _Pragma("unroll") for (int nt = 0; nt < 4; ++nt) { \
            ACC[nt] = MFMA16(hv, BH[((kc) * 4 + nt) * 64 + lane], ACC[nt]); \
            ACC[nt] = MFMA16(lv, BH[((kc) * 4 + nt) * 64 + lane], ACC[nt]); \
            ACC[nt] = MFMA16(hv, BL[((kc) * 4 + nt) * 64 + lane], ACC[nt]); } }
        if (bnsc) {
            pack8s_bn(xr + kh * 8, bnsc, kh * 8, hv, lv);           DO_KC3(0, accA)
            pack8s_bn(xr + 32 + kh * 8, bnsc, 32 + kh * 8, hv, lv); DO_KC3(1, accB)
        } else {
            pack8s(xr + kh * 8, hv, lv);        DO_KC3(0, accA)
            pack8s(xr + 32 + kh * 8, hv, lv);   DO_KC3(1, accB)
        }
        pack8fs(vme + 0, hv, lv);           DO_KC3(2, accA)
        pack8fs(vme + 8, hv, lv);           DO_KC3(3, accB)
        pack8fs(vmn + 0, hv, lv);           DO_KC3(4, accA)
        pack8fs(vmn + 8, hv, lv);           DO_KC3(5, accB)
        pack8fs(vmx + 0, hv, lv);           DO_KC3(6, accA)
        pack8fs(vmx + 8, hv, lv);           DO_KC3(7, accB)
#pragma unroll
        for (int j = 0; j < 16; ++j) sc16[j] = vme[j] * av;
        pack8fs(sc16 + 0, hv, lv);          DO_KC3(8, accA)
        pack8fs(sc16 + 8, hv, lv);          DO_KC3(9, accB)
#pragma unroll
        for (int j = 0; j < 16; ++j) sc16[j] = vmn[j] * av;
        pack8fs(sc16 + 0, hv, lv);          DO_KC3(10, accA)
        pack8fs(sc16 + 8, hv, lv);          DO_KC3(11, accB)
#pragma unroll
        for (int j = 0; j < 16; ++j) sc16[j] = vmx[j] * av;
        pack8fs(sc16 + 0, hv, lv);          DO_KC3(12, accA)
        pack8fs(sc16 + 8, hv, lv);          DO_KC3(13, accB)
#undef DO_KC3
#pragma unroll
        for (int nt = 0; nt < 4; ++nt) {
            float ps = 0.f, pq = 0.f;
#pragma unroll
            for (int r = 0; r < 4; ++r) {
                float v = accA[nt][r] + accB[nt][r] + cfv[nt];
                out_pre[((long)g * 16 + kh * 4 + r) * FF + nt * 16 + m] = v;
                ps += v;
                pq += v * v;
            }
            bs[nt] += ps;
            bq[nt] += pq;
        }
    }
#pragma unroll
    for (int nt = 0; nt < 4; ++nt) {
        atomicAdd(&sS[nt * 16 + m], bs[nt]);
        atomicAdd(&sQ[nt * 16 + m], bq[nt]);
    }
    __syncthreads();
    if (t < 64) {
        int rep = blockIdx.x & 7;
        atomicAdd(&bnsumR[rep * 64 + t], sS[t]);
        atomicAdd(&bnsumR[512 + rep * 64 + t], sQ[t]);
    }
}

// BN scale/shift precompute (sums 8 replicas): sc_sh[f] = s, sc_sh[64+f] = o
__global__ void bn_final(const float* __restrict__ bnsumR,
                         const float* __restrict__ gamma_l, const float* __restrict__ beta_l,
                         float* __restrict__ sc_sh) {
    int f = threadIdx.x;
    if (f < FF) {
        float s = 0.f, q = 0.f;
#pragma unroll
        for (int r = 0; r < 8; ++r) {
            s += bnsumR[r * 64 + f];
            q += bnsumR[512 + r * 64 + f];
        }
        float mu = s / (float)NN;
        float var = q / (float)NN - mu * mu;
        var = fmaxf(var, 0.f);
        float sc = gamma_l[f] * rsqrtf(var + EPSBN);
        sc_sh[f] = sc;
        sc_sh[FF + f] = beta_l[f] - mu * sc;
    }
}

// BN finalize + apply + ReLU (final layer output only)
__global__ void bn_apply2(const float* __restrict__ out_pre,
                          const float* __restrict__ bnsumR,
                          const float* __restrict__ gamma_l, const float* __restrict__ beta_l,
                          float* __restrict__ xout) {
    int f = threadIdx.x & 63;
    float s = 0.f, q = 0.f;
#pragma unroll
    for (int r = 0; r < 8; ++r) {
        s += bnsumR[r * 64 + f];
        q += bnsumR[512 + r * 64 + f];
    }
    float mu = s / (float)NN;
    float var = q / (float)NN - mu * mu;
    var = fmaxf(var, 0.f);
    float sc = gamma_l[f] * rsqrtf(var + EPSBN);
    float o = beta_l[f] - mu * sc;
    long i = (long)blockIdx.x * 256 + threadIdx.x;
    long stride = (long)gridDim.x * 256;   // multiple of 64 -> (j & 63) == f invariant
    for (long j = i; j < (long)NN * FF; j += stride) {
        xout[j] = fmaxf(fmaf(out_pre[j], sc, o), 0.f);
    }
}

extern "C" void kernel_launch(void* const* d_in, const int* in_sizes, int n_in,
                              void* d_out, int out_size, void* d_ws, size_t ws_size,
                              hipStream_t stream) {
    const float* x0    = (const float*)d_in[0];
    const int*   ei    = (const int*)d_in[1];
    const float* attr  = (const float*)d_in[2];
    const float* We    = (const float*)d_in[3];
    const float* be    = (const float*)d_in[4];
    const float* Wpre  = (const float*)d_in[5];
    const float* bpre  = (const float*)d_in[6];
    const float* Wpost = (const float*)d_in[7];
    const float* bpost = (const float*)d_in[8];
    const float* Wlin  = (const float*)d_in[9];
    const float* blin  = (const float*)d_in[10];
    const float* gamma = (const float*)d_in[11];
    const float* beta  = (const float*)d_in[12];
    float* out = (float*)d_out;

    // raise dynamic-LDS cap for node_mfma6 (160KB/CU available on gfx950)
    hipFuncSetAttribute((const void*)node_mfma6,
                        hipFuncAttributeMaxDynamicSharedMemorySize, (int)NODE_LDS);

    char* ws = (char*)d_ws;
    size_t off = 0;
    auto carve = [&](size_t bytes) -> void* {
        void* p = ws + off;
        off += (bytes + 255) & ~(size_t)255;
        return p;
    };
    const size_t NFb = (size_t)NN * FF * 4;
    float*    Weff   = (float*)carve(2 * EDIM * FF * 4);
    float*    beff   = (float*)carve(2 * FF * 4);
    float*    Wc     = (float*)carve(2 * 7 * FF * FF * 4);
    float*    cfold  = (float*)carve(2 * FF * 4);
    short*    WpreF  = (short*)carve(2 * 4096 * 2);
    short*    WeffF  = (short*)carve(2 * 2048 * 2);
    short*    WcFh   = (short*)carve(2 * WFRAG * 2);
    short*    WcFl   = (short*)carve(2 * WFRAG * 2);
    int*      srcp   = (int*)carve(NE * 4);
    short*    attrb  = (short*)carve((size_t)NE * EDIM * 2);   // 25.6 MB, CSR-ordered bf16 attr
    int*      rowptr = (int*)carve((NN + 1) * 4);
    int*      rowcnt = (int*)carve(NN * 4);
    int*      fill   = (int*)carve(NN * 4);
    int*      bc     = (int*)carve(NN * 4);
    float*    amp    = (float*)carve(NN * 4);
    int*      part   = (int*)carve(NSCB * 4);
    short*    xpb    = (short*)carve((size_t)NN * FF * 2);
    float*    meanb  = (float*)carve(NFb);
    float*    mnb    = (float*)carve(NFb);
    float*    mxb    = (float*)carve(NFb);
    float*    preA   = (float*)carve(NFb);   // layer-0 out_pre
    float*    preB   = (float*)carve(NFb);   // layer-1 out_pre
    float*    bnsumR = (float*)carve(1024 * 4);  // 8 replicas x (sum[64] | sumsq[64])
    float*    avglog = (float*)carve(4);
    float*    sc_sh  = (float*)carve(2 * FF * 4);
    int2*     srcperm = (int2*)preB;   // 6.4MB <= 12.8MB; preB first written by layer-1 node

    const int EB = (int)((NE + 255) / 256);

    // one-time build
    build_zero<<<196, 256, 0, stream>>>(rowcnt, fill, bc, avglog);
    hist_dst<<<EB, 256, 0, stream>>>(ei, rowcnt);
    scan_a<<<NSCB, SCB, 0, stream>>>(rowcnt, part);
    scan_b<<<1, 128, 0, stream>>>(part, rowptr);
    scan_c<<<NSCB, SCB, 0, stream>>>(rowcnt, part, rowptr);
    scatter_perm<<<EB, 256, 0, stream>>>(ei, rowptr, fill, srcperm);
    gather_attr<<<EB, 256, 0, stream>>>(srcperm, attr, srcp, attrb);
    degbc2<<<196, 256, 0, stream>>>(rowcnt, bc);
    avglog_kernel<<<128, 256, 0, stream>>>(bc, avglog);
    amp_kernel<<<196, 256, 0, stream>>>(rowcnt, avglog, amp);
    fold_kernel<<<32, 256, 0, stream>>>(We, be, Wpre, bpre, Wpost, bpost, Wlin, blin,
                                        Weff, beff, Wc, cfold);
    fragify_all<<<34, 256, 0, stream>>>(Wpre, Weff, Wc, WpreF, WeffF, WcFh, WcFl);

    for (int l = 0; l < NLAYER; ++l) {
        const float* xin  = (l == 0) ? x0 : ((l & 1) ? preA : preB);
        const float* bnsc = (l == 0) ? nullptr : sc_sh;
        float* pre        = (l & 1) ? preB : preA;

        xp_mfma<<<(NGRP + 3) / 4, 256, 0, stream>>>(xin, bnsc, WpreF + l * 4096, xpb, bnsumR);
        agg_fused<<<12500, 256, 0, stream>>>(rowptr, srcp, attrb, WeffF + l * 2048,
                                             beff + l * FF, xpb, meanb, mnb, mxb);
        node_mfma6<<<256, 256, NODE_LDS, stream>>>(xin, bnsc, meanb, mnb, mxb, amp,
                                                   WcFh + l * WFRAG, WcFl + l * WFRAG,
                                                   cfold + l * FF, pre, bnsumR);
        if (l < NLAYER - 1)
            bn_final<<<1, 64, 0, stream>>>(bnsumR, gamma + l * FF, beta + l * FF, sc_sh);
        else
            bn_apply2<<<4096, 256, 0, stream>>>(pre, bnsumR,
                                                gamma + l * FF, beta + l * FF, out);
    }
}

// Round 17
// 330.158 us; speedup vs baseline: 1.0335x; 1.0335x over previous
//
#include <hip/hip_runtime.h>
#include <math.h>

static constexpr int NN = 50000;     // nodes
static constexpr long NE = 800000;   // edges
static constexpr int FF = 64;        // features
static constexpr int EDIM = 16;      // edge attr dim
static constexpr int NLAYER = 2;
static constexpr float EPSBN = 1e-5f;
static constexpr int NGRP = NN / 16;         // 3125 node groups of 16
static constexpr int SCB = 512;              // scan block size
static constexpr int NSCB = (NN + SCB - 1) / SCB;  // 98
static constexpr int LDSW = 68;              // LDS row stride (floats): 2-way bank aliasing only
static constexpr int WFRAG = 28672;          // shorts per Wc fragment set (14kc x 4nt x 64 x 8)

typedef __attribute__((ext_vector_type(8))) short short8v;
typedef __attribute__((ext_vector_type(4))) float f32x4;

#define MFMA16(a, b, c) __builtin_amdgcn_mfma_f32_16x16x32_bf16(a, b, c, 0, 0, 0)

__device__ __forceinline__ short f2bf(float f) {
    unsigned u = __float_as_uint(f);
    unsigned r = u + 0x7FFFu + ((u >> 16) & 1u);   // RNE
    return (short)(r >> 16);
}
__device__ __forceinline__ float bf2f(unsigned short h) {
    return __uint_as_float(((unsigned)h) << 16);
}
__device__ __forceinline__ unsigned pk2(float lo, float hi) {
    return (unsigned)(unsigned short)f2bf(lo) | ((unsigned)(unsigned short)f2bf(hi) << 16);
}
__device__ __forceinline__ short8v pack8(const float* p) {
    const float4* q = (const float4*)p;
    float4 a = q[0], b = q[1];
    short8v v;
    v[0] = f2bf(a.x); v[1] = f2bf(a.y); v[2] = f2bf(a.z); v[3] = f2bf(a.w);
    v[4] = f2bf(b.x); v[5] = f2bf(b.y); v[6] = f2bf(b.z); v[7] = f2bf(b.w);
    return v;
}
// BN+ReLU applied during pack: y = max(v*s + o, 0); s=sc[f0+j], o=sc[64+f0+j]
__device__ __forceinline__ short8v pack8bn(const float* p, const float* sc, int f0) {
    const float4* q = (const float4*)p;
    float4 a = q[0], b = q[1];
    float v[8] = {a.x, a.y, a.z, a.w, b.x, b.y, b.z, b.w};
    short8v r;
#pragma unroll
    for (int j = 0; j < 8; ++j) {
        float y = fmaxf(fmaf(v[j], sc[f0 + j], sc[FF + f0 + j]), 0.f);
        r[j] = f2bf(y);
    }
    return r;
}
// split pack: hi = bf16(v), lo = bf16(v - hi)
__device__ __forceinline__ void pack8s(const float* p, short8v& hi, short8v& lo) {
    const float4* q = (const float4*)p;
    float4 a = q[0], b = q[1];
    float v[8] = {a.x, a.y, a.z, a.w, b.x, b.y, b.z, b.w};
#pragma unroll
    for (int j = 0; j < 8; ++j) {
        short h = f2bf(v[j]);
        hi[j] = h;
        lo[j] = f2bf(v[j] - bf2f((unsigned short)h));
    }
}
__device__ __forceinline__ void pack8s_bn(const float* p, const float* sc, int f0,
                                          short8v& hi, short8v& lo) {
    const float4* q = (const float4*)p;
    float4 a = q[0], b = q[1];
    float v[8] = {a.x, a.y, a.z, a.w, b.x, b.y, b.z, b.w};
#pragma unroll
    for (int j = 0; j < 8; ++j) {
        float y = fmaxf(fmaf(v[j], sc[f0 + j], sc[FF + f0 + j]), 0.f);
        short h = f2bf(y);
        hi[j] = h;
        lo[j] = f2bf(y - bf2f((unsigned short)h));
    }
}
__device__ __forceinline__ void pack8fs(const float* v, short8v& hi, short8v& lo) {
#pragma unroll
    for (int j = 0; j < 8; ++j) {
        short h = f2bf(v[j]);
        hi[j] = h;
        lo[j] = f2bf(v[j] - bf2f((unsigned short)h));
    }
}

// ---- fold weights (32 blocks: 2 layers x 16 slices) ----
__global__ void fold_kernel(const float* __restrict__ We, const float* __restrict__ be,
                            const float* __restrict__ Wpre, const float* __restrict__ bpre,
                            const float* __restrict__ Wpost, const float* __restrict__ bpost,
                            const float* __restrict__ Wlin, const float* __restrict__ blin,
                            float* __restrict__ Weff, float* __restrict__ beff,
                            float* __restrict__ Wc, float* __restrict__ cfold) {
    int l = blockIdx.x >> 4;
    int s = blockIdx.x & 15;
    int t = threadIdx.x;
    const float* We_l    = We    + l * EDIM * FF;
    const float* Wpre_e  = Wpre  + l * 2 * FF * FF + FF * FF;  // rows 64..127
    const float* Wpost_l = Wpost + l * 7 * FF * FF;
    const float* Wlin_l  = Wlin  + l * FF * FF;

    __shared__ float slin[FF * FF];
    __shared__ float spre[FF * FF];
    for (int i = t; i < FF * FF; i += blockDim.x) { slin[i] = Wlin_l[i]; spre[i] = Wpre_e[i]; }
    __syncthreads();

    for (int i = s * 256 + t; i < EDIM * FF; i += 16 * 256) {
        int j = i >> 6, f = i & 63;
        float a = 0.f;
        for (int k = 0; k < FF; ++k) a += We_l[j * FF + k] * spre[k * FF + f];
        Weff[l * EDIM * FF + i] = a;
    }
    for (int i = s * 256 + t; i < FF; i += 16 * 256) {
        float a = bpre[l * FF + i];
        for (int k = 0; k < FF; ++k) a += be[l * FF + k] * spre[k * FF + i];
        beff[l * FF + i] = a;
    }
    for (int i = s * 256 + t; i < 7 * FF * FF; i += 16 * 256) {
        int r = i >> 6, f = i & 63;
        float a = 0.f;
        for (int k = 0; k < FF; ++k) a += Wpost_l[r * FF + k] * slin[k * FF + f];
        Wc[l * 7 * FF * FF + i] = a;
    }
    for (int i = s * 256 + t; i < FF; i += 16 * 256) {
        float a = blin[l * FF + i];
        for (int k = 0; k < FF; ++k) a += bpost[l * FF + k] * slin[k * FF + i];
        cfold[l * FF + i] = a;
    }
}

// ---- all weight fragments in one launch. 34 blocks: 2 layers x (2 Wpre + 1 Weff + 14 Wc)
__global__ void fragify_all(const float* __restrict__ Wpre, const float* __restrict__ Weff,
                            const float* __restrict__ Wc,
                            short* __restrict__ WpreF, short* __restrict__ WeffF,
                            short* __restrict__ WcFh, short* __restrict__ WcFl) {
    int b = blockIdx.x;          // 0..33
    int l = b / 17, r = b % 17;
    int t = threadIdx.x;
    const float* src; short* dh; short* dl = nullptr; int kc, Kreal;
    if (r < 2)      { src = Wpre + (size_t)l * 2 * FF * FF; dh = WpreF + l * 4096;  kc = r;     Kreal = 64; }
    else if (r < 3) { src = Weff + (size_t)l * EDIM * FF;   dh = WeffF + l * 2048;  kc = 0;     Kreal = 16; }
    else            { src = Wc   + (size_t)l * 7 * FF * FF; dh = WcFh + l * WFRAG;
                      dl = WcFl + l * WFRAG;                                        kc = r - 3; Kreal = 448; }
    int idx = kc * 256 + t;
    int lane = idx & 63, nt = (idx >> 6) & 3;
    int m = lane & 15, kh = lane >> 4;
    short8v hv, lv;
#pragma unroll
    for (int j = 0; j < 8; ++j) {
        int k = kc * 32 + kh * 8 + j;
        float val = (k < Kreal) ? src[k * FF + nt * 16 + m] : 0.f;
        short h = f2bf(val);
        hv[j] = h;
        lv[j] = f2bf(val - bf2f((unsigned short)h));
    }
    ((short8v*)dh)[idx] = hv;
    if (dl) ((short8v*)dl)[idx] = lv;
}

// ================= CSR build phase ==========

__global__ void build_zero(int* __restrict__ rowcnt, int* __restrict__ fill,
                           int* __restrict__ bc, float* __restrict__ avglog) {
    long i = (long)blockIdx.x * 256 + threadIdx.x;
    long stride = (long)gridDim.x * 256;
    for (long j = i; j < NN; j += stride) { rowcnt[j] = 0; fill[j] = 0; bc[j] = 0; }
    if (i == 0) avglog[0] = 0.f;
}

__global__ void hist_dst(const int* __restrict__ ei, int* __restrict__ rowcnt) {
    long e = (long)blockIdx.x * 256 + threadIdx.x;
    if (e < NE) atomicAdd(&rowcnt[ei[NE + e]], 1);
}

// ---- hierarchical exclusive scan: rowcnt[NN] -> rowptr[NN+1] ----
__global__ void scan_a(const int* __restrict__ rowcnt, int* __restrict__ part) {
    __shared__ int red[SCB];
    int t = threadIdx.x;
    int i = blockIdx.x * SCB + t;
    red[t] = (i < NN) ? rowcnt[i] : 0;
    __syncthreads();
    for (int o = SCB / 2; o > 0; o >>= 1) {
        if (t < o) red[t] += red[t + o];
        __syncthreads();
    }
    if (t == 0) part[blockIdx.x] = red[0];
}

__global__ void scan_b(int* __restrict__ part, int* __restrict__ rowptr) {
    __shared__ int s[128];
    int t = threadIdx.x;
    int v = (t < NSCB) ? part[t] : 0;
    s[t] = v;
    __syncthreads();
    for (int o = 1; o < 128; o <<= 1) {
        int u = (t >= o) ? s[t - o] : 0;
        __syncthreads();
        s[t] += u;
        __syncthreads();
    }
    if (t < NSCB) part[t] = s[t] - v;          // exclusive block offset
    if (t == 127) rowptr[NN] = s[127];         // total
}

__global__ void scan_c(const int* __restrict__ rowcnt, const int* __restrict__ part,
                       int* __restrict__ rowptr) {
    __shared__ int s[SCB];
    int t = threadIdx.x;
    int i = blockIdx.x * SCB + t;
    int v = (i < NN) ? rowcnt[i] : 0;
    s[t] = v;
    __syncthreads();
    for (int o = 1; o < SCB; o <<= 1) {
        int u = (t >= o) ? s[t - o] : 0;
        __syncthreads();
        s[t] += u;
        __syncthreads();
    }
    if (i < NN) rowptr[i] = part[blockIdx.x] + s[t] - v;
}

// phase 1: scatter only an 8B (src, edge-id) record to the CSR slot
__global__ void scatter_perm(const int* __restrict__ ei, const int* __restrict__ rowptr,
                             int* __restrict__ fill, int2* __restrict__ srcperm) {
    long e = (long)blockIdx.x * 256 + threadIdx.x;
    if (e >= NE) return;
    int d = ei[NE + e];
    int p = rowptr[d] + atomicAdd(&fill[d], 1);
    srcperm[p] = make_int2(ei[e], (int)e);
}

// phase 2: sequential CSR positions -> coalesced srcp/attrb writes; random attr READS
__global__ void gather_attr(const int2* __restrict__ srcperm, const float* __restrict__ attr,
                            int* __restrict__ srcp, short* __restrict__ attrb) {
    long p = (long)blockIdx.x * 256 + threadIdx.x;
    if (p >= NE) return;
    int2 sp = srcperm[p];
    srcp[p] = sp.x;
    long e = sp.y;
    const float4* a4 = (const float4*)(attr + e * EDIM);
    float4 A = a4[0], B = a4[1], C = a4[2], D = a4[3];
    uint4 w0, w1;
    w0.x = pk2(A.x, A.y); w0.y = pk2(A.z, A.w); w0.z = pk2(B.x, B.y); w0.w = pk2(B.z, B.w);
    w1.x = pk2(C.x, C.y); w1.y = pk2(C.z, C.w); w1.z = pk2(D.x, D.y); w1.w = pk2(D.z, D.w);
    uint4* dst = (uint4*)(attrb + p * EDIM);
    dst[0] = w0; dst[1] = w1;
}

// LDS-privatized degree histogram
__global__ void degbc2(const int* __restrict__ rowcnt, int* __restrict__ bc) {
    __shared__ int h[256];
    int t = threadIdx.x;
    h[t] = 0;
    __syncthreads();
    for (long n = (long)blockIdx.x * 256 + t; n < NN; n += (long)gridDim.x * 256) {
        int d = rowcnt[n];
        if (d < 256) {
            atomicAdd(&h[d], 1);
        } else {
            if (d >= NN) d = NN - 1;
            atomicAdd(&bc[d], 1);
        }
    }
    __syncthreads();
    int v = h[t];
    if (v) atomicAdd(&bc[t], v);
}

__global__ void avglog_kernel(const int* __restrict__ bc, float* __restrict__ total) {
    float s = 0.f;
    for (long i = (long)blockIdx.x * 256 + threadIdx.x; i < NN; i += (long)gridDim.x * 256)
        s += logf((float)bc[i] + 1.f);
    for (int o = 32; o; o >>= 1) s += __shfl_down(s, o, 64);
    __shared__ float wsum[4];
    int lane = threadIdx.x & 63, wid = threadIdx.x >> 6;
    if (lane == 0) wsum[wid] = s;
    __syncthreads();
    if (threadIdx.x == 0) atomicAdd(total, wsum[0] + wsum[1] + wsum[2] + wsum[3]);
}

__global__ void amp_kernel(const int* __restrict__ cnt, const float* __restrict__ total,
                           float* __restrict__ amp) {
    long n = (long)blockIdx.x * 256 + threadIdx.x;
    if (n < NN) {
        float avg = total[0] / (float)NN;
        float sc = fmaxf((float)cnt[n], 1.f);
        amp[n] = logf(sc + 1.f) / avg;
    }
}

// ================= per-layer kernels ==========

// xp = BN?(xin) @ Wpre[0:64] -> bf16, via MFMA. wave per 16-node group.
// block 0 zeroes the 8-way replicated BN partial array (1024 floats).
__global__ __launch_bounds__(256) void xp_mfma(const float* __restrict__ xin,
                                               const float* __restrict__ bnsc,
                                               const short* __restrict__ WF,
                                               short* __restrict__ xpb,
                                               float* __restrict__ bnsumR) {
    int t = threadIdx.x;
    if (blockIdx.x == 0) {
        for (int i = t; i < 1024; i += 256) bnsumR[i] = 0.f;
    }
    int g = blockIdx.x * 4 + (t >> 6);
    if (g >= NGRP) return;
    int lane = t & 63, m = lane & 15, kh = lane >> 4;
    const float* xr = xin + (long)(g * 16 + m) * FF;
    short8v a0, a1;
    if (bnsc) {
        a0 = pack8bn(xr + kh * 8, bnsc, kh * 8);
        a1 = pack8bn(xr + 32 + kh * 8, bnsc, 32 + kh * 8);
    } else {
        a0 = pack8(xr + kh * 8);
        a1 = pack8(xr + 32 + kh * 8);
    }
    const short8v* BF = (const short8v*)WF;
    f32x4 acc[4];
#pragma unroll
    for (int nt = 0; nt < 4; ++nt) {
        f32x4 z = {0.f, 0.f, 0.f, 0.f};
        z = MFMA16(a0, BF[(0 * 4 + nt) * 64 + lane], z);
        z = MFMA16(a1, BF[(1 * 4 + nt) * 64 + lane], z);
        acc[nt] = z;
    }
#pragma unroll
    for (int nt = 0; nt < 4; ++nt)
#pragma unroll
        for (int r = 0; r < 4; ++r) {
            long node = g * 16 + kh * 4 + r;
            xpb[node * FF + nt * 16 + m] = f2bf(acc[nt][r]);
        }
}

// FUSED edge pipeline (R13-proven one-node-per-wave form): per 16-edge CSR batch,
// ep = attrb@Weff + beff via MFMA staged in padded LDS, then lane=feature serial
// reduce with 8 independent gathers in flight.
__global__ __launch_bounds__(256) void agg_fused(
    const int* __restrict__ rowptr, const int* __restrict__ srcp,
    const short* __restrict__ attrb, const short* __restrict__ WF,
    const float* __restrict__ beff_l, const short* __restrict__ xpb,
    float* __restrict__ meanb, float* __restrict__ mnb, float* __restrict__ mxb) {
    __shared__ float eph[4][16 * LDSW];
    int t = threadIdx.x;
    int wid = t >> 6, lane = t & 63;
    int m = lane & 15, kh = lane >> 4;
    int n = blockIdx.x * 4 + wid;
    if (n >= NN) return;   // no barriers in this kernel; waves independent
    float* lds = &eph[wid][0];
    const short8v* BF = (const short8v*)WF;
    float bfv[4];
#pragma unroll
    for (int nt = 0; nt < 4; ++nt) bfv[nt] = beff_l[nt * 16 + m];
    long r0 = rowptr[n], r1 = rowptr[n + 1];
    const float INF = __builtin_huge_valf();
    float sm = 0.f, mn = INF, mx = -INF;
    const unsigned short* xu = (const unsigned short*)xpb + lane;  // per-lane base

    for (long base = r0; base < r1; base += 16) {
        int cnt = (int)(((r1 - base) < 16) ? (r1 - base) : 16);
        long ea = base + m; if (ea > NE - 1) ea = NE - 1;   // tail rows masked later
        short8v a;
        if (kh < 2) {
            a = *(const short8v*)(attrb + ea * EDIM + kh * 8);
        } else {
#pragma unroll
            for (int j = 0; j < 8; ++j) a[j] = 0;
        }
        f32x4 ac0, ac1, ac2, ac3;
        {
            f32x4 z = {0.f, 0.f, 0.f, 0.f};
            ac0 = MFMA16(a, BF[0 * 64 + lane], z);
            ac1 = MFMA16(a, BF[1 * 64 + lane], z);
            ac2 = MFMA16(a, BF[2 * 64 + lane], z);
            ac3 = MFMA16(a, BF[3 * 64 + lane], z);
        }
#pragma unroll
        for (int r = 0; r < 4; ++r) {
            lds[(kh * 4 + r) * LDSW + 0 * 16 + m] = ac0[r] + bfv[0];
            lds[(kh * 4 + r) * LDSW + 1 * 16 + m] = ac1[r] + bfv[1];
            lds[(kh * 4 + r) * LDSW + 2 * 16 + m] = ac2[r] + bfv[2];
            lds[(kh * 4 + r) * LDSW + 3 * 16 + m] = ac3[r] + bfv[3];
        }
        int sv = srcp[base + (lane < cnt ? lane : cnt - 1)];
        int j = 0;
        for (; j + 8 <= cnt; j += 8) {
            unsigned o0 = (unsigned)__shfl(sv, j + 0) << 6;
            unsigned o1 = (unsigned)__shfl(sv, j + 1) << 6;
            unsigned o2 = (unsigned)__shfl(sv, j + 2) << 6;
            unsigned o3 = (unsigned)__shfl(sv, j + 3) << 6;
            unsigned o4 = (unsigned)__shfl(sv, j + 4) << 6;
            unsigned o5 = (unsigned)__shfl(sv, j + 5) << 6;
            unsigned o6 = (unsigned)__shfl(sv, j + 6) << 6;
            unsigned o7 = (unsigned)__shfl(sv, j + 7) << 6;
            float x0 = bf2f(xu[o0]);
            float x1 = bf2f(xu[o1]);
            float x2 = bf2f(xu[o2]);
            float x3 = bf2f(xu[o3]);
            float x4 = bf2f(xu[o4]);
            float x5 = bf2f(xu[o5]);
            float x6 = bf2f(xu[o6]);
            float x7 = bf2f(xu[o7]);
            float h0 = x0 + lds[(j + 0) * LDSW + lane];
            float h1 = x1 + lds[(j + 1) * LDSW + lane];
            float h2 = x2 + lds[(j + 2) * LDSW + lane];
            float h3 = x3 + lds[(j + 3) * LDSW + lane];
            float h4 = x4 + lds[(j + 4) * LDSW + lane];
            float h5 = x5 + lds[(j + 5) * LDSW + lane];
            float h6 = x6 + lds[(j + 6) * LDSW + lane];
            float h7 = x7 + lds[(j + 7) * LDSW + lane];
            sm += ((h0 + h1) + (h2 + h3)) + ((h4 + h5) + (h6 + h7));
            mn = fminf(mn, fminf(fminf(fminf(h0, h1), fminf(h2, h3)),
                                 fminf(fminf(h4, h5), fminf(h6, h7))));
            mx = fmaxf(mx, fmaxf(fmaxf(fmaxf(h0, h1), fmaxf(h2, h3)),
                                 fmaxf(fmaxf(h4, h5), fmaxf(h6, h7))));
        }
        for (; j < cnt; ++j) {
            unsigned o0 = (unsigned)__shfl(sv, j) << 6;
            float h = bf2f(xu[o0]) + lds[j * LDSW + lane];
            sm += h;
            mn = fminf(mn, h);
            mx = fmaxf(mx, h);
        }
    }
    int deg = (int)(r1 - r0);
    float inv = (deg > 0) ? (1.f / (float)deg) : 0.f;
    if (deg == 0) { mn = 0.f; mx = 0.f; }
    long o = (long)n * FF + lane;
    meanb[o] = sm * inv; mnb[o] = mn; mxb[o] = mx;
}

// node GEMM v4 (proven): 256 threads, wave = one 16-node group, full K, dual accumulator
// chains, weights streamed from L2 (latency hidden by ~12 resident waves/CU).
// BN partials: LDS reduce -> 8-way replicated global atomics (chain depth 32).
__global__ __launch_bounds__(256, 2) void node_mfma4(
    const float* __restrict__ xin, const float* __restrict__ bnsc,
    const float* __restrict__ meanb, const float* __restrict__ mnb,
    const float* __restrict__ mxb, const float* __restrict__ amp,
    const short* __restrict__ WFh, const short* __restrict__ WFl,
    const float* __restrict__ cfold_l,
    float* __restrict__ out_pre, float* __restrict__ bnsumR) {
    __shared__ float sS[FF], sQ[FF];
    int t = threadIdx.x;
    if (t < FF) { sS[t] = 0.f; sQ[t] = 0.f; }
    __syncthreads();
    int g = blockIdx.x * 4 + (t >> 6);
    bool act = (g < NGRP);
    int lane = t & 63, m = lane & 15, kh = lane >> 4;
    if (act) {
        long n = (long)g * 16 + m;
        float av = amp[n];
        const float* xr = xin + n * FF;
        float vme[16], vmn[16], vmx[16], sc16[16];
        {
            const float4* s4a = (const float4*)(meanb + n * FF + kh * 8);
            const float4* s4b = (const float4*)(meanb + n * FF + 32 + kh * 8);
            float4 a = s4a[0], b = s4a[1], c = s4b[0], d = s4b[1];
            vme[0]=a.x; vme[1]=a.y; vme[2]=a.z; vme[3]=a.w;
            vme[4]=b.x; vme[5]=b.y; vme[6]=b.z; vme[7]=b.w;
            vme[8]=c.x; vme[9]=c.y; vme[10]=c.z; vme[11]=c.w;
            vme[12]=d.x; vme[13]=d.y; vme[14]=d.z; vme[15]=d.w;
        }
        {
            const float4* s4a = (const float4*)(mnb + n * FF + kh * 8);
            const float4* s4b = (const float4*)(mnb + n * FF + 32 + kh * 8);
            float4 a = s4a[0], b = s4a[1], c = s4b[0], d = s4b[1];
            vmn[0]=a.x; vmn[1]=a.y; vmn[2]=a.z; vmn[3]=a.w;
            vmn[4]=b.x; vmn[5]=b.y; vmn[6]=b.z; vmn[7]=b.w;
            vmn[8]=c.x; vmn[9]=c.y; vmn[10]=c.z; vmn[11]=c.w;
            vmn[12]=d.x; vmn[13]=d.y; vmn[14]=d.z; vmn[15]=d.w;
        }
        {
            const float4* s4a = (const float4*)(mxb + n * FF + kh * 8);
            const float4* s4b = (const float4*)(mxb + n * FF + 32 + kh * 8);
            float4 a = s4a[0], b = s4a[1], c = s4b[0], d = s4b[1];
            vmx[0]=a.x; vmx[1]=a.y; vmx[2]=a.z; vmx[3]=a.w;
            vmx[4]=b.x; vmx[5]=b.y; vmx[6]=b.z; vmx[7]=b.w;
            vmx[8]=c.x; vmx[9]=c.y; vmx[10]=c.z; vmx[11]=c.w;
            vmx[12]=d.x; vmx[13]=d.y; vmx[14]=d.z; vmx[15]=d.w;
        }
        const short8v* BH = (const short8v*)WFh;
        const short8v* BL = (const short8v*)WFl;
        f32x4 accA[4], accB[4];
#pragma unroll
        for (int nt = 0; nt < 4; ++nt) {
            f32x4 z = {0.f, 0.f, 0.f, 0.f};
            accA[nt] = z; accB[nt] = z;
        }
        short8v hv, lv;
#define DO_KC3(kc, ACC) { \
        _Pragma("unroll") for (int nt = 0; nt < 4; ++nt) { \
            ACC[nt] = MFMA16(hv, BH[((kc) * 4 + nt) * 64 + lane], ACC[nt]); \
            ACC[nt] = MFMA16(lv, BH[((kc) * 4 + nt) * 64 + lane], ACC[nt]); \
            ACC[nt] = MFMA16(hv, BL[((kc) * 4 + nt) * 64 + lane], ACC[nt]); } }
        if (bnsc) {
            pack8s_bn(xr + kh * 8, bnsc, kh * 8, hv, lv);           DO_KC3(0, accA)
            pack8s_bn(xr + 32 + kh * 8, bnsc, 32 + kh * 8, hv, lv); DO_KC3(1, accB)
        } else {
            pack8s(xr + kh * 8, hv, lv);        DO_KC3(0, accA)
            pack8s(xr + 32 + kh * 8, hv, lv);   DO_KC3(1, accB)
        }
        pack8fs(vme + 0, hv, lv);           DO_KC3(2, accA)
        pack8fs(vme + 8, hv, lv);           DO_KC3(3, accB)
        pack8fs(vmn + 0, hv, lv);           DO_KC3(4, accA)
        pack8fs(vmn + 8, hv, lv);           DO_KC3(5, accB)
        pack8fs(vmx + 0, hv, lv);           DO_KC3(6, accA)
        pack8fs(vmx + 8, hv, lv);           DO_KC3(7, accB)
#pragma unroll
        for (int j = 0; j < 16; ++j) sc16[j] = vme[j] * av;
        pack8fs(sc16 + 0, hv, lv);          DO_KC3(8, accA)
        pack8fs(sc16 + 8, hv, lv);          DO_KC3(9, accB)
#pragma unroll
        for (int j = 0; j < 16; ++j) sc16[j] = vmn[j] * av;
        pack8fs(sc16 + 0, hv, lv);          DO_KC3(10, accA)
        pack8fs(sc16 + 8, hv, lv);          DO_KC3(11, accB)
#pragma unroll
        for (int j = 0; j < 16; ++j) sc16[j] = vmx[j] * av;
        pack8fs(sc16 + 0, hv, lv);          DO_KC3(12, accA)
        pack8fs(sc16 + 8, hv, lv);          DO_KC3(13, accB)
#undef DO_KC3
        float cfv[4];
#pragma unroll
        for (int nt = 0; nt < 4; ++nt) cfv[nt] = cfold_l[nt * 16 + m];
#pragma unroll
        for (int nt = 0; nt < 4; ++nt) {
            float ps = 0.f, pq = 0.f;
#pragma unroll
            for (int r = 0; r < 4; ++r) {
                float v = accA[nt][r] + accB[nt][r] + cfv[nt];
                out_pre[((long)g * 16 + kh * 4 + r) * FF + nt * 16 + m] = v;
                ps += v;
                pq += v * v;
            }
            atomicAdd(&sS[nt * 16 + m], ps);
            atomicAdd(&sQ[nt * 16 + m], pq);
        }
    }
    __syncthreads();
    if (t < FF) {
        int rep = blockIdx.x & 7;
        atomicAdd(&bnsumR[rep * 64 + t], sS[t]);
        atomicAdd(&bnsumR[512 + rep * 64 + t], sQ[t]);
    }
}

// BN scale/shift precompute (sums 8 replicas): sc_sh[f] = s, sc_sh[64+f] = o
__global__ void bn_final(const float* __restrict__ bnsumR,
                         const float* __restrict__ gamma_l, const float* __restrict__ beta_l,
                         float* __restrict__ sc_sh) {
    int f = threadIdx.x;
    if (f < FF) {
        float s = 0.f, q = 0.f;
#pragma unroll
        for (int r = 0; r < 8; ++r) {
            s += bnsumR[r * 64 + f];
            q += bnsumR[512 + r * 64 + f];
        }
        float mu = s / (float)NN;
        float var = q / (float)NN - mu * mu;
        var = fmaxf(var, 0.f);
        float sc = gamma_l[f] * rsqrtf(var + EPSBN);
        sc_sh[f] = sc;
        sc_sh[FF + f] = beta_l[f] - mu * sc;
    }
}

// BN finalize + apply + ReLU (final layer output only)
__global__ void bn_apply2(const float* __restrict__ out_pre,
                          const float* __restrict__ bnsumR,
                          const float* __restrict__ gamma_l, const float* __restrict__ beta_l,
                          float* __restrict__ xout) {
    int f = threadIdx.x & 63;
    float s = 0.f, q = 0.f;
#pragma unroll
    for (int r = 0; r < 8; ++r) {
        s += bnsumR[r * 64 + f];
        q += bnsumR[512 + r * 64 + f];
    }
    float mu = s / (float)NN;
    float var = q / (float)NN - mu * mu;
    var = fmaxf(var, 0.f);
    float sc = gamma_l[f] * rsqrtf(var + EPSBN);
    float o = beta_l[f] - mu * sc;
    long i = (long)blockIdx.x * 256 + threadIdx.x;
    long stride = (long)gridDim.x * 256;   // multiple of 64 -> (j & 63) == f invariant
    for (long j = i; j < (long)NN * FF; j += stride) {
        xout[j] = fmaxf(fmaf(out_pre[j], sc, o), 0.f);
    }
}

extern "C" void kernel_launch(void* const* d_in, const int* in_sizes, int n_in,
                              void* d_out, int out_size, void* d_ws, size_t ws_size,
                              hipStream_t stream) {
    const float* x0    = (const float*)d_in[0];
    const int*   ei    = (const int*)d_in[1];
    const float* attr  = (const float*)d_in[2];
    const float* We    = (const float*)d_in[3];
    const float* be    = (const float*)d_in[4];
    const float* Wpre  = (const float*)d_in[5];
    const float* bpre  = (const float*)d_in[6];
    const float* Wpost = (const float*)d_in[7];
    const float* bpost = (const float*)d_in[8];
    const float* Wlin  = (const float*)d_in[9];
    const float* blin  = (const float*)d_in[10];
    const float* gamma = (const float*)d_in[11];
    const float* beta  = (const float*)d_in[12];
    float* out = (float*)d_out;

    char* ws = (char*)d_ws;
    size_t off = 0;
    auto carve = [&](size_t bytes) -> void* {
        void* p = ws + off;
        off += (bytes + 255) & ~(size_t)255;
        return p;
    };
    const size_t NFb = (size_t)NN * FF * 4;
    float*    Weff   = (float*)carve(2 * EDIM * FF * 4);
    float*    beff   = (float*)carve(2 * FF * 4);
    float*    Wc     = (float*)carve(2 * 7 * FF * FF * 4);
    float*    cfold  = (float*)carve(2 * FF * 4);
    short*    WpreF  = (short*)carve(2 * 4096 * 2);
    short*    WeffF  = (short*)carve(2 * 2048 * 2);
    short*    WcFh   = (short*)carve(2 * WFRAG * 2);
    short*    WcFl   = (short*)carve(2 * WFRAG * 2);
    int*      srcp   = (int*)carve(NE * 4);
    short*    attrb  = (short*)carve((size_t)NE * EDIM * 2);   // 25.6 MB, CSR-ordered bf16 attr
    int*      rowptr = (int*)carve((NN + 1) * 4);
    int*      rowcnt = (int*)carve(NN * 4);
    int*      fill   = (int*)carve(NN * 4);
    int*      bc     = (int*)carve(NN * 4);
    float*    amp    = (float*)carve(NN * 4);
    int*      part   = (int*)carve(NSCB * 4);
    short*    xpb    = (short*)carve((size_t)NN * FF * 2);
    float*    meanb  = (float*)carve(NFb);
    float*    mnb    = (float*)carve(NFb);
    float*    mxb    = (float*)carve(NFb);
    float*    preA   = (float*)carve(NFb);   // layer-0 out_pre
    float*    preB   = (float*)carve(NFb);   // layer-1 out_pre
    float*    bnsumR = (float*)carve(1024 * 4);  // 8 replicas x (sum[64] | sumsq[64])
    float*    avglog = (float*)carve(4);
    float*    sc_sh  = (float*)carve(2 * FF * 4);
    int2*     srcperm = (int2*)preB;   // 6.4MB <= 12.8MB; preB first written by layer-1 node

    const int EB = (int)((NE + 255) / 256);

    // one-time build
    build_zero<<<196, 256, 0, stream>>>(rowcnt, fill, bc, avglog);
    hist_dst<<<EB, 256, 0, stream>>>(ei, rowcnt);
    scan_a<<<NSCB, SCB, 0, stream>>>(rowcnt, part);
    scan_b<<<1, 128, 0, stream>>>(part, rowptr);
    scan_c<<<NSCB, SCB, 0, stream>>>(rowcnt, part, rowptr);
    scatter_perm<<<EB, 256, 0, stream>>>(ei, rowptr, fill, srcperm);
    gather_attr<<<EB, 256, 0, stream>>>(srcperm, attr, srcp, attrb);
    degbc2<<<196, 256, 0, stream>>>(rowcnt, bc);
    avglog_kernel<<<128, 256, 0, stream>>>(bc, avglog);
    amp_kernel<<<196, 256, 0, stream>>>(rowcnt, avglog, amp);
    fold_kernel<<<32, 256, 0, stream>>>(We, be, Wpre, bpre, Wpost, bpost, Wlin, blin,
                                        Weff, beff, Wc, cfold);
    fragify_all<<<34, 256, 0, stream>>>(Wpre, Weff, Wc, WpreF, WeffF, WcFh, WcFl);

    for (int l = 0; l < NLAYER; ++l) {
        const float* xin  = (l == 0) ? x0 : ((l & 1) ? preA : preB);
        const float* bnsc = (l == 0) ? nullptr : sc_sh;
        float* pre        = (l & 1) ? preB : preA;

        xp_mfma<<<(NGRP + 3) / 4, 256, 0, stream>>>(xin, bnsc, WpreF + l * 4096, xpb, bnsumR);
        agg_fused<<<12500, 256, 0, stream>>>(rowptr, srcp, attrb, WeffF + l * 2048,
                                             beff + l * FF, xpb, meanb, mnb, mxb);
        node_mfma4<<<(NGRP + 3) / 4, 256, 0, stream>>>(xin, bnsc, meanb, mnb, mxb, amp,
                                                       WcFh + l * WFRAG, WcFl + l * WFRAG,
                                                       cfold + l * FF, pre, bnsumR);
        if (l < NLAYER - 1)
            bn_final<<<1, 64, 0, stream>>>(bnsumR, gamma + l * FF, beta + l * FF, sc_sh);
        else
            bn_apply2<<<4096, 256, 0, stream>>>(pre, bnsumR,
                                                gamma + l * FF, beta + l * FF, out);
    }
}